// Round 7
// baseline (249.222 us; speedup 1.0000x reference)
//
#include <hip/hip_runtime.h>
#include <hip/hip_bf16.h>
#include <math.h>

#define NEG_SLOPE 0.2f
#define PGROUPS 32

typedef __attribute__((ext_vector_type(8))) short bf16x8;
typedef __attribute__((ext_vector_type(4))) float f32x4;
typedef __attribute__((ext_vector_type(2))) float f32x2_t;

__device__ __forceinline__ float lrelu(float a) { return a >= 0.f ? a : NEG_SLOPE * a; }
__device__ __forceinline__ unsigned short f2bu(float v) {
  unsigned u = __float_as_uint(v);
  u += 0x7fffu + ((u >> 16) & 1u);  // RNE
  return (unsigned short)(u >> 16);
}
// fp8 e4m3 (OCP on gfx950) HW conversions
__device__ __forceinline__ unsigned char f2fp8(float v) {
  return (unsigned char)(__builtin_amdgcn_cvt_pk_fp8_f32(v, v, 0, false) & 0xFF);
}

// ==== prep: W1/W2 transposed cast (blocks < wBlocks) | node hist + bucket hist ====
__global__ __launch_bounds__(256) void prep_kernel(
    const float* __restrict__ W1, unsigned short* __restrict__ w1t,  // [256][128]
    const float* __restrict__ W2, unsigned short* __restrict__ w2t,  // [64][256]
    const int* __restrict__ ei, int* __restrict__ bhist, int* __restrict__ nhist,
    int E0, int Etot, int NBUCK, int wBlocks, int histBlocks) {
  __shared__ int hsm[256];
  int t = threadIdx.x;
  if (blockIdx.x < (unsigned)wBlocks) {
    const int tot1 = 128 * 256, tot2 = 256 * 64;
    for (int i = blockIdx.x * 256 + t; i < tot1 + tot2; i += wBlocks * 256) {
      if (i < tot1) { int k = i >> 8, n = i & 255; w1t[n * 128 + k] = f2bu(W1[i]); }
      else { int j = i - tot1; int k = j >> 6, n = j & 63; w2t[n * 256 + k] = f2bu(W2[j]); }
    }
  } else {
    int bid = blockIdx.x - wBlocks;
    hsm[t] = 0;
    __syncthreads();
    for (int e = bid * 256 + t; e < Etot; e += histBlocks * 256) {
      int dst = (e < E0) ? ei[E0 + e] : (e - E0);
      atomicAdd(&hsm[dst >> 8], 1);   // bucket-level (LDS-aggregated)
      atomicAdd(&nhist[dst], 1);      // node-level (direct; ~17 adds/address)
    }
    __syncthreads();
    if (t < NBUCK && hsm[t]) atomicAdd(&bhist[t], hsm[t]);
  }
}

// ================= bucket scan (also zeroes pooled_grp) =================
__global__ __launch_bounds__(256) void bucket_scan_kernel(const int* __restrict__ bhist,
    int* __restrict__ bucketOff, int* __restrict__ rowptrN,
    float* __restrict__ pooled_grp, int NBUCK, int Etot) {
  __shared__ int s[256];
  int t = threadIdx.x;
  int v = (t < NBUCK) ? bhist[t] : 0;
  s[t] = v;
  __syncthreads();
  for (int off = 1; off < 256; off <<= 1) {
    int u = (t >= off) ? s[t - off] : 0;
    __syncthreads();
    s[t] += u;
    __syncthreads();
  }
  int excl = s[t] - v;
  if (t < NBUCK) bucketOff[t] = excl;
  if (t == 0) { bucketOff[NBUCK] = Etot; *rowptrN = Etot; }
  for (int i = t; i < PGROUPS * 64; i += 256) pooled_grp[i] = 0.f;
}

// ======= rowptr: per-bucket intra-scan of nhist -> rowptr + cursor (reads 200KB) =======
__global__ __launch_bounds__(256) void rowptr_kernel(const int* __restrict__ nhist,
    const int* __restrict__ bucketOff, int* __restrict__ rowptr, int* __restrict__ cursor,
    int N) {
  int b = blockIdx.x, t = threadIdx.x;
  int n = (b << 8) + t;
  __shared__ int s[256];
  int v = (n < N) ? nhist[n] : 0;
  s[t] = v;
  __syncthreads();
  for (int off = 1; off < 256; off <<= 1) {
    int u = (t >= off) ? s[t - off] : 0;
    __syncthreads();
    s[t] += u;
    __syncthreads();
  }
  if (n < N) {
    int r = bucketOff[b] + s[t] - v;
    rowptr[n] = r;
    cursor[n] = r;
  }
}

// ===== gemm1 tile: 64 rows x ALL 256 cols per block (x read ONCE).
__device__ void gemm1_tile(const float* __restrict__ x,
    const unsigned short* __restrict__ BT, unsigned char* __restrict__ C8,
    const float* __restrict__ att_s, const float* __restrict__ att_d,
    float* __restrict__ as_, float* __restrict__ ad_,
    int M, int by, char* smem) {
  unsigned short (*Al)[40] = (unsigned short (*)[40])smem;            // 64*40*2  = 5120 B
  unsigned short (*Bt)[40] = (unsigned short (*)[40])(smem + 5120);   // 256*40*2 = 20480 B
  const int tid = threadIdx.x;
  const int row0 = by * 64;
  const int lane = tid & 63, wave = tid >> 6;
  const int l15 = lane & 15, q = lane >> 4;

  f32x4 acc[4][4] = {};
  const int rr = tid >> 2, rc = (tid & 3) * 8;  // A-stage: row 0..63, k-off {0,8,16,24}

  for (int k0 = 0; k0 < 128; k0 += 32) {
    // stage A from f32 x, cast to bf16 (8 floats/thread)
    float4 v0 = make_float4(0.f, 0.f, 0.f, 0.f), v1 = v0;
    if (row0 + rr < M) {
      const float* ap = x + (size_t)(row0 + rr) * 128 + k0 + rc;
      v0 = *(const float4*)ap;
      v1 = *(const float4*)(ap + 4);
    }
    *(ushort4*)&Al[rr][rc] = make_ushort4(f2bu(v0.x), f2bu(v0.y), f2bu(v0.z), f2bu(v0.w));
    *(ushort4*)&Al[rr][rc + 4] = make_ushort4(f2bu(v1.x), f2bu(v1.y), f2bu(v1.z), f2bu(v1.w));
    // stage B: thread t stages full row t (32 shorts)
    {
      const ushort4* bp = (const ushort4*)(BT + (size_t)tid * 128 + k0);
#pragma unroll
      for (int i = 0; i < 8; i++) *(ushort4*)&Bt[tid][i * 4] = bp[i];
    }
    __syncthreads();
    bf16x8 af[4], bf[4];
#pragma unroll
    for (int mi = 0; mi < 4; mi++)
      af[mi] = *(const bf16x8*)&Al[mi * 16 + l15][q * 8];
#pragma unroll
    for (int ni = 0; ni < 4; ni++)
      bf[ni] = *(const bf16x8*)&Bt[wave * 64 + ni * 16 + l15][q * 8];
#pragma unroll
    for (int mi = 0; mi < 4; mi++)
#pragma unroll
      for (int ni = 0; ni < 4; ni++)
        acc[mi][ni] = __builtin_amdgcn_mfma_f32_16x16x32_bf16(af[mi], bf[ni], acc[mi][ni], 0, 0, 0);
    __syncthreads();
  }
  // epilogue: fp8 store + in-wave alpha (wave == head)
  float atts[4], attd[4];
#pragma unroll
  for (int ni = 0; ni < 4; ni++) {
    atts[ni] = att_s[wave * 64 + ni * 16 + l15];
    attd[ni] = att_d[wave * 64 + ni * 16 + l15];
  }
#pragma unroll
  for (int mi = 0; mi < 4; mi++) {
#pragma unroll
    for (int r = 0; r < 4; r++) {
      int grow = row0 + mi * 16 + q * 4 + r;
      bool ok = grow < M;
      if (ok) {
#pragma unroll
        for (int ni = 0; ni < 4; ni++)
          C8[(size_t)grow * 256 + wave * 64 + ni * 16 + l15] = f2fp8(acc[mi][ni][r]);
      }
      float vs = acc[mi][0][r] * atts[0] + acc[mi][1][r] * atts[1]
               + acc[mi][2][r] * atts[2] + acc[mi][3][r] * atts[3];
      float vd = acc[mi][0][r] * attd[0] + acc[mi][1][r] * attd[1]
               + acc[mi][2][r] * attd[2] + acc[mi][3][r] * attd[3];
#pragma unroll
      for (int off = 1; off < 16; off <<= 1) {
        vs += __shfl_xor(vs, off);
        vd += __shfl_xor(vd, off);
      }
      if (ok && l15 == 0) {
        as_[(size_t)grow * 4 + wave] = vs;
        ad_[(size_t)grow * 4 + wave] = vd;
      }
    }
  }
}

// ========== fused: direct CSR scatter (blocks < NSC) || gemm1 ==========
__global__ __launch_bounds__(256) void gemm1_scatter_kernel(
    const float* __restrict__ x, const unsigned short* __restrict__ BT,
    unsigned char* __restrict__ C8, const float* __restrict__ att_s,
    const float* __restrict__ att_d, float* __restrict__ as_, float* __restrict__ ad_,
    int M, const int* __restrict__ ei, int* __restrict__ cursor, int* __restrict__ csr_src,
    int E0, int Etot, int NSC) {
  __shared__ __align__(16) char smem[25600];
  if (blockIdx.x < (unsigned)NSC) {
    // direct scatter: pos = cursor[d]++, csr_src[pos] = s
    for (int e = blockIdx.x * 256 + threadIdx.x; e < Etot; e += NSC * 256) {
      int s, d;
      if (e < E0) { s = ei[e]; d = ei[E0 + e]; } else { s = d = e - E0; }
      int pos = atomicAdd(&cursor[d], 1);
      csr_src[pos] = s;
    }
  } else {
    gemm1_tile(x, BT, C8, att_s, att_d, as_, ad_, M, blockIdx.x - NSC, smem);
  }
}

// accumulate one fp8 16-ch row into 8 float2 accumulators (v_pk_fma_f32 path)
#define ACCV(W, X) do {                                                        \
    f32x2_t w2_; w2_.x = (W); w2_.y = (W);                                     \
    av[0] += w2_ * __builtin_amdgcn_cvt_pk_f32_fp8((X).x, false);              \
    av[1] += w2_ * __builtin_amdgcn_cvt_pk_f32_fp8((X).x, true);               \
    av[2] += w2_ * __builtin_amdgcn_cvt_pk_f32_fp8((X).y, false);              \
    av[3] += w2_ * __builtin_amdgcn_cvt_pk_f32_fp8((X).y, true);               \
    av[4] += w2_ * __builtin_amdgcn_cvt_pk_f32_fp8((X).z, false);              \
    av[5] += w2_ * __builtin_amdgcn_cvt_pk_f32_fp8((X).z, true);               \
    av[6] += w2_ * __builtin_amdgcn_cvt_pk_f32_fp8((X).w, false);              \
    av[7] += w2_ * __builtin_amdgcn_cvt_pk_f32_fp8((X).w, true);               \
  } while (0)

// ====== layer-1 aggregate: quarter-wave per node, 16 ch/lane, direct idx loads, MLP 8 ======
__global__ __launch_bounds__(256) void aggr1_kernel(const int* __restrict__ rowptr,
    const int* __restrict__ csr_src, const float* __restrict__ as_,
    const float* __restrict__ ad_, const uint4* __restrict__ h1f8,  // [N][16] uint4
    const float* __restrict__ b1, unsigned short* __restrict__ out1, int Nn) {
  int lane = threadIdx.x & 63, wv = threadIdx.x >> 6;
  int q = lane >> 4, l15 = lane & 15;
  int n = (blockIdx.x * 4 + wv) * 4 + q;
  if (n >= Nn) return;
  int row = rowptr[n], deg = rowptr[n + 1] - row;
  int hh = l15 >> 2;
  float adv = ad_[n * 4 + hh];
  const uint4* hb = h1f8 + l15;
  f32x2_t av[8] = {};
  float wsum = 0.f;
  for (int s = 0; s < deg; s += 8) {
    int id[8];
    float al[8];
    uint4 xv[8];
#pragma unroll
    for (int u = 0; u < 8; u++) {
      int p = s + u;
      if (p > deg - 1) p = deg - 1;       // clamp: always in-bounds
      id[u] = csr_src[row + p];           // uniform across quarter -> broadcast
    }
#pragma unroll
    for (int u = 0; u < 8; u++) al[u] = as_[id[u] * 4 + hh];
#pragma unroll
    for (int u = 0; u < 8; u++) xv[u] = hb[(size_t)id[u] * 16];
#pragma unroll
    for (int u = 0; u < 8; u++) {
      float w = (s + u < deg) ? __expf(lrelu(al[u] + adv)) : 0.f;
      wsum += w;
      ACCV(w, xv[u]);
    }
  }
  float vinv = 1.f / wsum;
  int c0i = l15 * 16;
  unsigned short ob[16];
#pragma unroll
  for (int k = 0; k < 4; k++) {
    float4 bb = *(const float4*)(b1 + c0i + k * 4);
    float r0 = fmaf(av[k * 2].x, vinv, bb.x);
    float r1 = fmaf(av[k * 2].y, vinv, bb.y);
    float r2 = fmaf(av[k * 2 + 1].x, vinv, bb.z);
    float r3 = fmaf(av[k * 2 + 1].y, vinv, bb.w);
    ob[k * 4 + 0] = f2bu(r0 > 0.f ? r0 : 0.f);
    ob[k * 4 + 1] = f2bu(r1 > 0.f ? r1 : 0.f);
    ob[k * 4 + 2] = f2bu(r2 > 0.f ? r2 : 0.f);
    ob[k * 4 + 3] = f2bu(r3 > 0.f ? r3 : 0.f);
  }
  *(ushort4*)(out1 + (size_t)n * 256 + c0i) = *(ushort4*)&ob[0];
  *(ushort4*)(out1 + (size_t)n * 256 + c0i + 4) = *(ushort4*)&ob[4];
  *(ushort4*)(out1 + (size_t)n * 256 + c0i + 8) = *(ushort4*)&ob[8];
  *(ushort4*)(out1 + (size_t)n * 256 + c0i + 12) = *(ushort4*)&ob[12];
}

// ===== gemm2 (generic small-LDS tile): A bf16 [M][256], BT [64][256] -> h2 fp8 + alpha =====
__global__ __launch_bounds__(256) void gemm2_kernel(const unsigned short* __restrict__ A,
    const unsigned short* __restrict__ BT, unsigned char* __restrict__ C8,
    const float* __restrict__ att_s, const float* __restrict__ att_d,
    float* __restrict__ as_, float* __restrict__ ad_, int M) {
  const int K = 256, Ncol = 64;
  __shared__ __align__(16) char smem[11264];
  unsigned short (*Al)[40] = (unsigned short (*)[40])smem;           // 5120 B
  unsigned short (*Bt)[40] = (unsigned short (*)[40])(smem + 5120);  // 5120 B
  float* sal = (float*)(smem + 10240);  // [2][64]
  float* sad = (float*)(smem + 10752);  // [2][64]
  const int tid = threadIdx.x;
  const int row0 = blockIdx.x * 64;
  const int lane = tid & 63, wave = tid >> 6;
  const int wm = wave >> 1, wn = wave & 1;
  const int l15 = lane & 15, q = lane >> 4;

  f32x4 acc[2][2] = {};
  const int rr = tid >> 2, rc = (tid & 3) * 8;

  for (int k0 = 0; k0 < K; k0 += 32) {
    ushort4 av0 = make_ushort4(0, 0, 0, 0), av1 = av0;
    if (row0 + rr < M) {
      const ushort4* ap = (const ushort4*)(A + (size_t)(row0 + rr) * K + k0 + rc);
      av0 = ap[0]; av1 = ap[1];
    }
    *(ushort4*)&Al[rr][rc] = av0;
    *(ushort4*)&Al[rr][rc + 4] = av1;
    {
      const ushort4* bp = (const ushort4*)(BT + (size_t)rr * K + k0 + rc);
      *(ushort4*)&Bt[rr][rc] = bp[0];
      *(ushort4*)&Bt[rr][rc + 4] = bp[1];
    }
    __syncthreads();
    bf16x8 af[2], bf[2];
#pragma unroll
    for (int mi = 0; mi < 2; mi++)
      af[mi] = *(const bf16x8*)&Al[wm * 32 + mi * 16 + l15][q * 8];
#pragma unroll
    for (int ni = 0; ni < 2; ni++)
      bf[ni] = *(const bf16x8*)&Bt[wn * 32 + ni * 16 + l15][q * 8];
#pragma unroll
    for (int mi = 0; mi < 2; mi++)
#pragma unroll
      for (int ni = 0; ni < 2; ni++)
        acc[mi][ni] = __builtin_amdgcn_mfma_f32_16x16x32_bf16(af[mi], bf[ni], acc[mi][ni], 0, 0, 0);
    __syncthreads();
  }
#pragma unroll
  for (int mi = 0; mi < 2; mi++) {
#pragma unroll
    for (int r = 0; r < 4; r++) {
      int grow = row0 + wm * 32 + mi * 16 + q * 4 + r;
      if (grow < M) {
#pragma unroll
        for (int ni = 0; ni < 2; ni++) {
          int gcol = wn * 32 + ni * 16 + l15;
          C8[(size_t)grow * Ncol + gcol] = f2fp8(acc[mi][ni][r]);
        }
      }
    }
  }
  float atts0 = att_s[wn * 32 + l15], atts1 = att_s[wn * 32 + 16 + l15];
  float attd0 = att_d[wn * 32 + l15], attd1 = att_d[wn * 32 + 16 + l15];
#pragma unroll
  for (int mi = 0; mi < 2; mi++) {
#pragma unroll
    for (int r = 0; r < 4; r++) {
      float vs = acc[mi][0][r] * atts0 + acc[mi][1][r] * atts1;
      float vd = acc[mi][0][r] * attd0 + acc[mi][1][r] * attd1;
#pragma unroll
      for (int off = 1; off < 16; off <<= 1) {
        vs += __shfl_xor(vs, off);
        vd += __shfl_xor(vd, off);
      }
      if (l15 == 0) {
        int rl = wm * 32 + mi * 16 + q * 4 + r;
        sal[wn * 64 + rl] = vs;
        sad[wn * 64 + rl] = vd;
      }
    }
  }
  __syncthreads();
  if (tid < 64) {
    int grow = row0 + tid;
    if (grow < M) {
      as_[grow] = sal[tid] + sal[64 + tid];
      ad_[grow] = sad[tid] + sad[64 + tid];
    }
  }
}

// ====== layer-2 aggregate + relu + pool: direct uniform idx loads, unroll 8, pk-fma ======
__global__ __launch_bounds__(256) void aggr2_pool_kernel(const int* __restrict__ rowptr,
    const int* __restrict__ csr_src, const float* __restrict__ as_,
    const float* __restrict__ ad_, const unsigned* __restrict__ h2f8,
    const float* __restrict__ b2, float* __restrict__ pooled_grp, int Nn) {
  int lane = threadIdx.x & 63, wv = threadIdx.x >> 6;
  int q = lane >> 4, l15 = lane & 15;
  int c0 = l15 * 4;
  const unsigned* hb = h2f8 + l15;
  f32x2_t pv0 = {0.f, 0.f}, pv1 = {0.f, 0.f};
  int stream = (blockIdx.x * 4 + wv) * 4 + q;
  int nstreams = gridDim.x * 16;
  for (int n = stream; n < Nn; n += nstreams) {
    int row = rowptr[n], deg = rowptr[n + 1] - row;
    float adv = ad_[n];
    f32x2_t a01 = {0.f, 0.f}, a23 = {0.f, 0.f};
    float wsum = 0.f;
    for (int s = 0; s < deg; s += 8) {
      int id[8];
      float al[8];
      unsigned xv[8];
#pragma unroll
      for (int u = 0; u < 8; u++) {
        int p = s + u;
        if (p > deg - 1) p = deg - 1;
        id[u] = csr_src[row + p];
      }
#pragma unroll
      for (int u = 0; u < 8; u++) al[u] = as_[id[u]];
#pragma unroll
      for (int u = 0; u < 8; u++) xv[u] = hb[(size_t)id[u] * 16];
#pragma unroll
      for (int u = 0; u < 8; u++) {
        float w = (s + u < deg) ? __expf(lrelu(al[u] + adv)) : 0.f;
        wsum += w;
        f32x2_t w2_; w2_.x = w; w2_.y = w;
        a01 += w2_ * __builtin_amdgcn_cvt_pk_f32_fp8(xv[u], false);
        a23 += w2_ * __builtin_amdgcn_cvt_pk_f32_fp8(xv[u], true);
      }
    }
    float vinv = 1.f / wsum;
    float4 bb = *(const float4*)(b2 + c0);
    float r0 = fmaf(a01.x, vinv, bb.x), r1 = fmaf(a01.y, vinv, bb.y);
    float r2 = fmaf(a23.x, vinv, bb.z), r3 = fmaf(a23.y, vinv, bb.w);
    pv0.x += r0 > 0.f ? r0 : 0.f; pv0.y += r1 > 0.f ? r1 : 0.f;
    pv1.x += r2 > 0.f ? r2 : 0.f; pv1.y += r3 > 0.f ? r3 : 0.f;
  }
  __shared__ float4 sred[4][4][16];
  sred[wv][q][l15] = make_float4(pv0.x, pv0.y, pv1.x, pv1.y);
  __syncthreads();
  if (threadIdx.x < 64) {
    int slot = threadIdx.x >> 2, comp = threadIdx.x & 3;
    float acc = 0.f;
#pragma unroll
    for (int i = 0; i < 4; i++)
#pragma unroll
      for (int j = 0; j < 4; j++) {
        float4 v = sred[i][j][slot];
        acc += comp == 0 ? v.x : (comp == 1 ? v.y : (comp == 2 ? v.z : v.w));
      }
    atomicAdd(&pooled_grp[(blockIdx.x & (PGROUPS - 1)) * 64 + slot * 4 + comp], acc);
  }
}

// ================= pooled_grp[32][64] -> fc + log_softmax (one block) =================
__global__ __launch_bounds__(64) void pool_head_kernel(const float* __restrict__ pooled_grp,
    const float* __restrict__ fc_w, const float* __restrict__ fc_b,
    float* __restrict__ out, float invN) {
  int t = threadIdx.x;
  __shared__ float pl[64];
  __shared__ float lg[40];
  __shared__ float lse;
  float acc = 0.f;
#pragma unroll
  for (int g = 0; g < PGROUPS; g++) acc += pooled_grp[g * 64 + t];
  pl[t] = acc * invN;
  __syncthreads();
  if (t < 40) {
    float sm = fc_b[t];
    for (int c = 0; c < 64; c++) sm = fmaf(pl[c], fc_w[c * 40 + t], sm);
    lg[t] = sm;
  }
  __syncthreads();
  if (t == 0) {
    float m = -1e30f;
    for (int j = 0; j < 40; j++) m = fmaxf(m, lg[j]);
    float su = 0.f;
    for (int j = 0; j < 40; j++) su += expf(lg[j] - m);
    lse = m + logf(su);
  }
  __syncthreads();
  if (t < 40) out[t] = lg[t] - lse;
}

extern "C" void kernel_launch(void* const* d_in, const int* in_sizes, int n_in,
                              void* d_out, int out_size, void* d_ws, size_t ws_size,
                              hipStream_t stream) {
  const float* x        = (const float*)d_in[0];
  const int*   ei       = (const int*)d_in[1];
  const float* W1       = (const float*)d_in[2];
  const float* att_src1 = (const float*)d_in[3];
  const float* att_dst1 = (const float*)d_in[4];
  const float* b1       = (const float*)d_in[5];
  const float* W2       = (const float*)d_in[6];
  const float* att_src2 = (const float*)d_in[7];
  const float* att_dst2 = (const float*)d_in[8];
  const float* b2       = (const float*)d_in[9];
  const float* fc_w     = (const float*)d_in[10];
  const float* fc_b     = (const float*)d_in[11];
  float* out = (float*)d_out;

  const int N    = in_sizes[0] / 128;  // 50000
  const int E0   = in_sizes[1] / 2;    // 800000
  const int Etot = E0 + N;
  const int NBUCK = (N + 255) >> 8;               // 196
  const int NSC  = 128;                           // scatter blocks (grid-stride)
  const int GBY  = (N + 63) / 64;                 // 782
  const int AGG2_BLOCKS = 2048;

  char* wsb = (char*)d_ws;
  size_t o = 0;
  auto alloc = [&](size_t bytes) { char* p = wsb + o; o += (bytes + 15) & ~(size_t)15; return p; };
  unsigned short* w1t  = (unsigned short*)alloc(256 * 128 * 2);       // transposed [256][128]
  unsigned short* w2t  = (unsigned short*)alloc(64 * 256 * 2);        // transposed [64][256]
  unsigned char*  h1f8 = (unsigned char*)alloc((size_t)N * 256);      // h1 fp8
  unsigned char*  h2   = (unsigned char*)alloc((size_t)N * 64);       // h2 fp8
  unsigned short* out1 = (unsigned short*)alloc((size_t)N * 256 * 2); // bf16
  float* as1  = (float*)alloc((size_t)N * 4 * 4);
  float* ad1  = (float*)alloc((size_t)N * 4 * 4);
  float* as2  = (float*)alloc((size_t)N * 4);
  float* ad2  = (float*)alloc((size_t)N * 4);
  int* rowptr = (int*)alloc((size_t)(N + 1) * 4);
  // zero block: bhist[256] + nhist[N]  (single memset)
  int* bhist  = (int*)alloc((256 + (size_t)N) * 4);
  int* nhist  = bhist + 256;
  int* bucketOff = (int*)alloc(257 * 4);
  int* cursor = (int*)alloc((size_t)N * 4);
  int* csr_src = (int*)alloc((size_t)Etot * 4);
  float* pooled_grp = (float*)alloc((size_t)PGROUPS * 64 * 4);

  dim3 blk(256);

  // ---- prep: W transpose-cast || node+bucket hist ----
  hipMemsetAsync(bhist, 0, (256 + (size_t)N) * sizeof(int), stream);
  prep_kernel<<<16 + 256, blk, 0, stream>>>(W1, w1t, W2, w2t, ei, bhist, nhist,
                                            E0, Etot, NBUCK, 16, 256);
  bucket_scan_kernel<<<1, blk, 0, stream>>>(bhist, bucketOff, rowptr + N,
                                            pooled_grp, NBUCK, Etot);
  rowptr_kernel<<<NBUCK, blk, 0, stream>>>(nhist, bucketOff, rowptr, cursor, N);

  // ---- gemm1 (64x256 blocks, x read once) || direct CSR scatter ----
  gemm1_scatter_kernel<<<NSC + GBY, blk, 0, stream>>>(
      x, w1t, h1f8, att_src1, att_dst1, as1, ad1, N,
      ei, cursor, csr_src, E0, Etot, NSC);

  // ---- layer-1 aggregate (quarter-wave, direct idx loads, MLP 8) ----
  aggr1_kernel<<<(N + 15) / 16, blk, 0, stream>>>(rowptr, csr_src, as1, ad1,
                                                  (const uint4*)h1f8, b1, out1, N);

  // ---- layer 2: gemm2 (+alpha2 epilogue), aggregate + grouped pool atomics ----
  gemm2_kernel<<<GBY, blk, 0, stream>>>(out1, w2t, h2, att_src2, att_dst2, as2, ad2, N);
  aggr2_pool_kernel<<<AGG2_BLOCKS, blk, 0, stream>>>(rowptr, csr_src, as2, ad2,
                                                     (const unsigned*)h2, b2, pooled_grp, N);

  // ---- epilogue ----
  pool_head_kernel<<<1, 64, 0, stream>>>(pooled_grp, fc_w, fc_b, out, 1.0f / (float)N);
}

// Round 9
// 247.704 us; speedup vs baseline: 1.0061x; 1.0061x over previous
//
#include <hip/hip_runtime.h>
#include <hip/hip_bf16.h>
#include <math.h>

#define NEG_SLOPE 0.2f
#define CHUNK2 2048
#define PGROUPS 32

typedef __attribute__((ext_vector_type(8))) short bf16x8;
typedef __attribute__((ext_vector_type(4))) float f32x4;
typedef __attribute__((ext_vector_type(2))) float f32x2_t;

__device__ __forceinline__ float lrelu(float a) { return a >= 0.f ? a : NEG_SLOPE * a; }
__device__ __forceinline__ unsigned short f2bu(float v) {
  unsigned u = __float_as_uint(v);
  u += 0x7fffu + ((u >> 16) & 1u);  // RNE
  return (unsigned short)(u >> 16);
}
// fp8 e4m3 (OCP on gfx950) HW conversions
__device__ __forceinline__ unsigned char f2fp8(float v) {
  return (unsigned char)(__builtin_amdgcn_cvt_pk_fp8_f32(v, v, 0, false) & 0xFF);
}

// ==== prep: W1/W2 transposed cast (blocks < wBlocks) | bucket hist + node hist ====
__global__ __launch_bounds__(256) void prep_kernel(
    const float* __restrict__ W1, unsigned short* __restrict__ w1t,  // [256][128]
    const float* __restrict__ W2, unsigned short* __restrict__ w2t,  // [64][256]
    const int* __restrict__ ei, int* __restrict__ bhist, int* __restrict__ nhist,
    int E0, int Etot, int NBUCK, int wBlocks, int histBlocks) {
  __shared__ int hsm[256];
  int t = threadIdx.x;
  if (blockIdx.x < (unsigned)wBlocks) {
    const int tot1 = 128 * 256, tot2 = 256 * 64;
    for (int i = blockIdx.x * 256 + t; i < tot1 + tot2; i += wBlocks * 256) {
      if (i < tot1) { int k = i >> 8, n = i & 255; w1t[n * 128 + k] = f2bu(W1[i]); }
      else { int j = i - tot1; int k = j >> 6, n = j & 63; w2t[n * 256 + k] = f2bu(W2[j]); }
    }
  } else {
    int bid = blockIdx.x - wBlocks;
    hsm[t] = 0;
    __syncthreads();
    for (int e = bid * 256 + t; e < Etot; e += histBlocks * 256) {
      int dst = (e < E0) ? ei[E0 + e] : (e - E0);
      atomicAdd(&hsm[dst >> 8], 1);   // bucket-level (LDS-aggregated)
      atomicAdd(&nhist[dst], 1);      // node-level (~17 adds/address, proven cheap R7)
    }
    __syncthreads();
    if (t < NBUCK && hsm[t]) atomicAdd(&bhist[t], hsm[t]);
  }
}

// ================= bucket scan (also zeroes pooled_grp) =================
__global__ __launch_bounds__(256) void bucket_scan_kernel(const int* __restrict__ bhist,
    int* __restrict__ bucketOff, int* __restrict__ cursor, int* __restrict__ rowptrN,
    float* __restrict__ pooled_grp, int NBUCK, int Etot) {
  __shared__ int s[256];
  int t = threadIdx.x;
  int v = (t < NBUCK) ? bhist[t] : 0;
  s[t] = v;
  __syncthreads();
  for (int off = 1; off < 256; off <<= 1) {
    int u = (t >= off) ? s[t - off] : 0;
    __syncthreads();
    s[t] += u;
    __syncthreads();
  }
  int excl = s[t] - v;
  if (t < NBUCK) { bucketOff[t] = excl; cursor[t] = excl; }
  if (t == 0) { bucketOff[NBUCK] = Etot; *rowptrN = Etot; }
  for (int i = t; i < PGROUPS * 64; i += 256) pooled_grp[i] = 0.f;
}

// ======= rowptr: per-bucket intra-scan of nhist -> rowptr (reads 200KB; proven cheap R7) =======
__global__ __launch_bounds__(256) void rowptr_kernel(const int* __restrict__ nhist,
    const int* __restrict__ bucketOff, int* __restrict__ rowptr, int N) {
  int b = blockIdx.x, t = threadIdx.x;
  int n = (b << 8) + t;
  __shared__ int s[256];
  int v = (n < N) ? nhist[n] : 0;
  s[t] = v;
  __syncthreads();
  for (int off = 1; off < 256; off <<= 1) {
    int u = (t >= off) ? s[t - off] : 0;
    __syncthreads();
    s[t] += u;
    __syncthreads();
  }
  if (n < N) rowptr[n] = bucketOff[b] + s[t] - v;
}

// ===== gemm1 tile: 64 rows x ALL 256 cols per block (x read ONCE).
__device__ void gemm1_tile(const float* __restrict__ x,
    const unsigned short* __restrict__ BT, unsigned char* __restrict__ C8,
    const float* __restrict__ att_s, const float* __restrict__ att_d,
    float* __restrict__ as_, float* __restrict__ ad_,
    int M, int by, char* smem) {
  unsigned short (*Al)[40] = (unsigned short (*)[40])smem;            // 64*40*2  = 5120 B
  unsigned short (*Bt)[40] = (unsigned short (*)[40])(smem + 5120);   // 256*40*2 = 20480 B
  const int tid = threadIdx.x;
  const int row0 = by * 64;
  const int lane = tid & 63, wave = tid >> 6;
  const int l15 = lane & 15, q = lane >> 4;

  f32x4 acc[4][4] = {};
  const int rr = tid >> 2, rc = (tid & 3) * 8;  // A-stage: row 0..63, k-off {0,8,16,24}

  for (int k0 = 0; k0 < 128; k0 += 32) {
    // stage A from f32 x, cast to bf16 (8 floats/thread)
    float4 v0 = make_float4(0.f, 0.f, 0.f, 0.f), v1 = v0;
    if (row0 + rr < M) {
      const float* ap = x + (size_t)(row0 + rr) * 128 + k0 + rc;
      v0 = *(const float4*)ap;
      v1 = *(const float4*)(ap + 4);
    }
    *(ushort4*)&Al[rr][rc] = make_ushort4(f2bu(v0.x), f2bu(v0.y), f2bu(v0.z), f2bu(v0.w));
    *(ushort4*)&Al[rr][rc + 4] = make_ushort4(f2bu(v1.x), f2bu(v1.y), f2bu(v1.z), f2bu(v1.w));
    // stage B: thread t stages full row t (32 shorts)
    {
      const ushort4* bp = (const ushort4*)(BT + (size_t)tid * 128 + k0);
#pragma unroll
      for (int i = 0; i < 8; i++) *(ushort4*)&Bt[tid][i * 4] = bp[i];
    }
    __syncthreads();
    bf16x8 af[4], bf[4];
#pragma unroll
    for (int mi = 0; mi < 4; mi++)
      af[mi] = *(const bf16x8*)&Al[mi * 16 + l15][q * 8];
#pragma unroll
    for (int ni = 0; ni < 4; ni++)
      bf[ni] = *(const bf16x8*)&Bt[wave * 64 + ni * 16 + l15][q * 8];
#pragma unroll
    for (int mi = 0; mi < 4; mi++)
#pragma unroll
      for (int ni = 0; ni < 4; ni++)
        acc[mi][ni] = __builtin_amdgcn_mfma_f32_16x16x32_bf16(af[mi], bf[ni], acc[mi][ni], 0, 0, 0);
    __syncthreads();
  }
  // epilogue: fp8 store + in-wave alpha (wave == head)
  float atts[4], attd[4];
#pragma unroll
  for (int ni = 0; ni < 4; ni++) {
    atts[ni] = att_s[wave * 64 + ni * 16 + l15];
    attd[ni] = att_d[wave * 64 + ni * 16 + l15];
  }
#pragma unroll
  for (int mi = 0; mi < 4; mi++) {
#pragma unroll
    for (int r = 0; r < 4; r++) {
      int grow = row0 + mi * 16 + q * 4 + r;
      bool ok = grow < M;
      if (ok) {
#pragma unroll
        for (int ni = 0; ni < 4; ni++)
          C8[(size_t)grow * 256 + wave * 64 + ni * 16 + l15] = f2fp8(acc[mi][ni][r]);
      }
      float vs = acc[mi][0][r] * atts[0] + acc[mi][1][r] * atts[1]
               + acc[mi][2][r] * atts[2] + acc[mi][3][r] * atts[3];
      float vd = acc[mi][0][r] * attd[0] + acc[mi][1][r] * attd[1]
               + acc[mi][2][r] * attd[2] + acc[mi][3][r] * attd[3];
#pragma unroll
      for (int off = 1; off < 16; off <<= 1) {
        vs += __shfl_xor(vs, off);
        vd += __shfl_xor(vd, off);
      }
      if (ok && l15 == 0) {
        as_[(size_t)grow * 4 + wave] = vs;
        ad_[(size_t)grow * 4 + wave] = vd;
      }
    }
  }
}

// ====== fused: bucket scatter (bucket-LOCAL pairs writes, blocks < NSC) || gemm1 ======
__global__ __launch_bounds__(256) void gemm1_scatter_kernel(
    const float* __restrict__ x, const unsigned short* __restrict__ BT,
    unsigned char* __restrict__ C8, const float* __restrict__ att_s,
    const float* __restrict__ att_d, float* __restrict__ as_, float* __restrict__ ad_,
    int M, const int* __restrict__ ei, int* __restrict__ cursor, int* __restrict__ pairs,
    int E0, int Etot, int NBUCK, int NSC) {
  __shared__ __align__(16) char smem[25600];
  if (blockIdx.x < (unsigned)NSC) {
    int2* stage = (int2*)smem;            // 16384 B
    int* h = (int*)(smem + 16384);        // 1024 B
    int* base = (int*)(smem + 17408);     // 1024 B
    int t = threadIdx.x;
    int e0 = blockIdx.x * CHUNK2;
    h[t] = 0;
    __syncthreads();
    int cnt = Etot - e0;
    if (cnt > CHUNK2) cnt = CHUNK2;
    for (int i = t; i < cnt; i += 256) {
      int e = e0 + i;
      int s, d;
      if (e < E0) { s = ei[e]; d = ei[E0 + e]; } else { s = d = e - E0; }
      stage[i] = make_int2((s << 8) | (d & 255), d >> 8);
      atomicAdd(&h[d >> 8], 1);
    }
    __syncthreads();
    if (t < NBUCK && h[t]) base[t] = atomicAdd(&cursor[t], h[t]);
    __syncthreads();
    for (int i = t; i < cnt; i += 256) {
      int2 p = stage[i];
      int pos = atomicAdd(&base[p.y], 1);
      pairs[pos] = p.x;
    }
  } else {
    gemm1_tile(x, BT, C8, att_s, att_d, as_, ad_, M, blockIdx.x - NSC, smem);
  }
}

// ====== csr_build v2: placement-only (hist pass eliminated — ex seeded from rowptr) ======
__global__ __launch_bounds__(256) void csr_build_kernel(const int* __restrict__ pairs,
    const int* __restrict__ bucketOff, const int* __restrict__ rowptr,
    int* __restrict__ csr_src, int N) {
  int b = blockIdx.x, t = threadIdx.x;
  int base = bucketOff[b], cnt = bucketOff[b + 1] - base;
  int n0 = b << 8;
  __shared__ int ex[256];
  int n = n0 + t;
  ex[t] = (n < N) ? rowptr[n] : 0;
  __syncthreads();
  for (int i = t; i < cnt; i += 256) {
    int p = pairs[base + i];
    int pos = atomicAdd(&ex[p & 255], 1);
    csr_src[pos] = ((unsigned)p) >> 8;
  }
}

// accumulate one fp8 16-ch row into 8 float2 accumulators (v_pk_fma_f32 path)
#define ACCV(W, X) do {                                                        \
    f32x2_t w2_; w2_.x = (W); w2_.y = (W);                                     \
    av[0] += w2_ * __builtin_amdgcn_cvt_pk_f32_fp8((X).x, false);              \
    av[1] += w2_ * __builtin_amdgcn_cvt_pk_f32_fp8((X).x, true);               \
    av[2] += w2_ * __builtin_amdgcn_cvt_pk_f32_fp8((X).y, false);              \
    av[3] += w2_ * __builtin_amdgcn_cvt_pk_f32_fp8((X).y, true);               \
    av[4] += w2_ * __builtin_amdgcn_cvt_pk_f32_fp8((X).z, false);              \
    av[5] += w2_ * __builtin_amdgcn_cvt_pk_f32_fp8((X).z, true);               \
    av[6] += w2_ * __builtin_amdgcn_cvt_pk_f32_fp8((X).w, false);              \
    av[7] += w2_ * __builtin_amdgcn_cvt_pk_f32_fp8((X).w, true);               \
  } while (0)

// ====== layer-1 aggregate: quarter-wave per node, 16 ch/lane, direct idx loads, MLP 8 ======
__global__ __launch_bounds__(256) void aggr1_kernel(const int* __restrict__ rowptr,
    const int* __restrict__ csr_src, const float* __restrict__ as_,
    const float* __restrict__ ad_, const uint4* __restrict__ h1f8,  // [N][16] uint4
    const float* __restrict__ b1, unsigned short* __restrict__ out1, int Nn) {
  int lane = threadIdx.x & 63, wv = threadIdx.x >> 6;
  int q = lane >> 4, l15 = lane & 15;
  int n = (blockIdx.x * 4 + wv) * 4 + q;
  if (n >= Nn) return;
  int row = rowptr[n], deg = rowptr[n + 1] - row;
  int hh = l15 >> 2;
  float adv = ad_[n * 4 + hh];
  const uint4* hb = h1f8 + l15;
  f32x2_t av[8] = {};
  float wsum = 0.f;
  for (int s = 0; s < deg; s += 8) {
    int id[8];
    float al[8];
    uint4 xv[8];
#pragma unroll
    for (int u = 0; u < 8; u++) {
      int p = s + u;
      if (p > deg - 1) p = deg - 1;       // clamp: always in-bounds
      id[u] = csr_src[row + p];           // uniform across quarter -> broadcast
    }
#pragma unroll
    for (int u = 0; u < 8; u++) al[u] = as_[id[u] * 4 + hh];
#pragma unroll
    for (int u = 0; u < 8; u++) xv[u] = hb[(size_t)id[u] * 16];
#pragma unroll
    for (int u = 0; u < 8; u++) {
      float w = (s + u < deg) ? __expf(lrelu(al[u] + adv)) : 0.f;
      wsum += w;
      ACCV(w, xv[u]);
    }
  }
  float vinv = 1.f / wsum;
  int c0i = l15 * 16;
  unsigned short ob[16];
#pragma unroll
  for (int k = 0; k < 4; k++) {
    float4 bb = *(const float4*)(b1 + c0i + k * 4);
    float r0 = fmaf(av[k * 2].x, vinv, bb.x);
    float r1 = fmaf(av[k * 2].y, vinv, bb.y);
    float r2 = fmaf(av[k * 2 + 1].x, vinv, bb.z);
    float r3 = fmaf(av[k * 2 + 1].y, vinv, bb.w);
    ob[k * 4 + 0] = f2bu(r0 > 0.f ? r0 : 0.f);
    ob[k * 4 + 1] = f2bu(r1 > 0.f ? r1 : 0.f);
    ob[k * 4 + 2] = f2bu(r2 > 0.f ? r2 : 0.f);
    ob[k * 4 + 3] = f2bu(r3 > 0.f ? r3 : 0.f);
  }
  *(ushort4*)(out1 + (size_t)n * 256 + c0i) = *(ushort4*)&ob[0];
  *(ushort4*)(out1 + (size_t)n * 256 + c0i + 4) = *(ushort4*)&ob[4];
  *(ushort4*)(out1 + (size_t)n * 256 + c0i + 8) = *(ushort4*)&ob[8];
  *(ushort4*)(out1 + (size_t)n * 256 + c0i + 12) = *(ushort4*)&ob[12];
}

// ===== gemm2 (generic small-LDS tile): A bf16 [M][256], BT [64][256] -> h2 fp8 + alpha =====
__global__ __launch_bounds__(256) void gemm2_kernel(const unsigned short* __restrict__ A,
    const unsigned short* __restrict__ BT, unsigned char* __restrict__ C8,
    const float* __restrict__ att_s, const float* __restrict__ att_d,
    float* __restrict__ as_, float* __restrict__ ad_, int M) {
  const int K = 256, Ncol = 64;
  __shared__ __align__(16) char smem[11264];
  unsigned short (*Al)[40] = (unsigned short (*)[40])smem;           // 5120 B
  unsigned short (*Bt)[40] = (unsigned short (*)[40])(smem + 5120);  // 5120 B
  float* sal = (float*)(smem + 10240);  // [2][64]
  float* sad = (float*)(smem + 10752);  // [2][64]
  const int tid = threadIdx.x;
  const int row0 = blockIdx.x * 64;
  const int lane = tid & 63, wave = tid >> 6;
  const int wm = wave >> 1, wn = wave & 1;
  const int l15 = lane & 15, q = lane >> 4;

  f32x4 acc[2][2] = {};
  const int rr = tid >> 2, rc = (tid & 3) * 8;

  for (int k0 = 0; k0 < K; k0 += 32) {
    ushort4 av0 = make_ushort4(0, 0, 0, 0), av1 = av0;
    if (row0 + rr < M) {
      const ushort4* ap = (const ushort4*)(A + (size_t)(row0 + rr) * K + k0 + rc);
      av0 = ap[0]; av1 = ap[1];
    }
    *(ushort4*)&Al[rr][rc] = av0;
    *(ushort4*)&Al[rr][rc + 4] = av1;
    {
      const ushort4* bp = (const ushort4*)(BT + (size_t)rr * K + k0 + rc);
      *(ushort4*)&Bt[rr][rc] = bp[0];
      *(ushort4*)&Bt[rr][rc + 4] = bp[1];
    }
    __syncthreads();
    bf16x8 af[2], bf[2];
#pragma unroll
    for (int mi = 0; mi < 2; mi++)
      af[mi] = *(const bf16x8*)&Al[wm * 32 + mi * 16 + l15][q * 8];
#pragma unroll
    for (int ni = 0; ni < 2; ni++)
      bf[ni] = *(const bf16x8*)&Bt[wn * 32 + ni * 16 + l15][q * 8];
#pragma unroll
    for (int mi = 0; mi < 2; mi++)
#pragma unroll
      for (int ni = 0; ni < 2; ni++)
        acc[mi][ni] = __builtin_amdgcn_mfma_f32_16x16x32_bf16(af[mi], bf[ni], acc[mi][ni], 0, 0, 0);
    __syncthreads();
  }
#pragma unroll
  for (int mi = 0; mi < 2; mi++) {
#pragma unroll
    for (int r = 0; r < 4; r++) {
      int grow = row0 + wm * 32 + mi * 16 + q * 4 + r;
      if (grow < M) {
#pragma unroll
        for (int ni = 0; ni < 2; ni++) {
          int gcol = wn * 32 + ni * 16 + l15;
          C8[(size_t)grow * Ncol + gcol] = f2fp8(acc[mi][ni][r]);
        }
      }
    }
  }
  float atts0 = att_s[wn * 32 + l15], atts1 = att_s[wn * 32 + 16 + l15];
  float attd0 = att_d[wn * 32 + l15], attd1 = att_d[wn * 32 + 16 + l15];
#pragma unroll
  for (int mi = 0; mi < 2; mi++) {
#pragma unroll
    for (int r = 0; r < 4; r++) {
      float vs = acc[mi][0][r] * atts0 + acc[mi][1][r] * atts1;
      float vd = acc[mi][0][r] * attd0 + acc[mi][1][r] * attd1;
#pragma unroll
      for (int off = 1; off < 16; off <<= 1) {
        vs += __shfl_xor(vs, off);
        vd += __shfl_xor(vd, off);
      }
      if (l15 == 0) {
        int rl = wm * 32 + mi * 16 + q * 4 + r;
        sal[wn * 64 + rl] = vs;
        sad[wn * 64 + rl] = vd;
      }
    }
  }
  __syncthreads();
  if (tid < 64) {
    int grow = row0 + tid;
    if (grow < M) {
      as_[grow] = sal[tid] + sal[64 + tid];
      ad_[grow] = sad[tid] + sad[64 + tid];
    }
  }
}

// ====== layer-2 aggregate + relu + pool: direct uniform idx loads, unroll 8, pk-fma ======
__global__ __launch_bounds__(256) void aggr2_pool_kernel(const int* __restrict__ rowptr,
    const int* __restrict__ csr_src, const float* __restrict__ as_,
    const float* __restrict__ ad_, const unsigned* __restrict__ h2f8,
    const float* __restrict__ b2, float* __restrict__ pooled_grp, int Nn) {
  int lane = threadIdx.x & 63, wv = threadIdx.x >> 6;
  int q = lane >> 4, l15 = lane & 15;
  int c0 = l15 * 4;
  const unsigned* hb = h2f8 + l15;
  f32x2_t pv0 = {0.f, 0.f}, pv1 = {0.f, 0.f};
  int stream = (blockIdx.x * 4 + wv) * 4 + q;
  int nstreams = gridDim.x * 16;
  for (int n = stream; n < Nn; n += nstreams) {
    int row = rowptr[n], deg = rowptr[n + 1] - row;
    float adv = ad_[n];
    f32x2_t a01 = {0.f, 0.f}, a23 = {0.f, 0.f};
    float wsum = 0.f;
    for (int s = 0; s < deg; s += 8) {
      int id[8];
      float al[8];
      unsigned xv[8];
#pragma unroll
      for (int u = 0; u < 8; u++) {
        int p = s + u;
        if (p > deg - 1) p = deg - 1;
        id[u] = csr_src[row + p];
      }
#pragma unroll
      for (int u = 0; u < 8; u++) al[u] = as_[id[u]];
#pragma unroll
      for (int u = 0; u < 8; u++) xv[u] = hb[(size_t)id[u] * 16];
#pragma unroll
      for (int u = 0; u < 8; u++) {
        float w = (s + u < deg) ? __expf(lrelu(al[u] + adv)) : 0.f;
        wsum += w;
        f32x2_t w2_; w2_.x = w; w2_.y = w;
        a01 += w2_ * __builtin_amdgcn_cvt_pk_f32_fp8(xv[u], false);
        a23 += w2_ * __builtin_amdgcn_cvt_pk_f32_fp8(xv[u], true);
      }
    }
    float vinv = 1.f / wsum;
    float4 bb = *(const float4*)(b2 + c0);
    float r0 = fmaf(a01.x, vinv, bb.x), r1 = fmaf(a01.y, vinv, bb.y);
    float r2 = fmaf(a23.x, vinv, bb.z), r3 = fmaf(a23.y, vinv, bb.w);
    pv0.x += r0 > 0.f ? r0 : 0.f; pv0.y += r1 > 0.f ? r1 : 0.f;
    pv1.x += r2 > 0.f ? r2 : 0.f; pv1.y += r3 > 0.f ? r3 : 0.f;
  }
  __shared__ float4 sred[4][4][16];
  sred[wv][q][l15] = make_float4(pv0.x, pv0.y, pv1.x, pv1.y);
  __syncthreads();
  if (threadIdx.x < 64) {
    int slot = threadIdx.x >> 2, comp = threadIdx.x & 3;
    float acc = 0.f;
#pragma unroll
    for (int i = 0; i < 4; i++)
#pragma unroll
      for (int j = 0; j < 4; j++) {
        float4 v = sred[i][j][slot];
        acc += comp == 0 ? v.x : (comp == 1 ? v.y : (comp == 2 ? v.z : v.w));
      }
    atomicAdd(&pooled_grp[(blockIdx.x & (PGROUPS - 1)) * 64 + slot * 4 + comp], acc);
  }
}

// ================= pooled_grp[32][64] -> fc + log_softmax (one block) =================
__global__ __launch_bounds__(64) void pool_head_kernel(const float* __restrict__ pooled_grp,
    const float* __restrict__ fc_w, const float* __restrict__ fc_b,
    float* __restrict__ out, float invN) {
  int t = threadIdx.x;
  __shared__ float pl[64];
  __shared__ float lg[40];
  __shared__ float lse;
  float acc = 0.f;
#pragma unroll
  for (int g = 0; g < PGROUPS; g++) acc += pooled_grp[g * 64 + t];
  pl[t] = acc * invN;
  __syncthreads();
  if (t < 40) {
    float sm = fc_b[t];
    for (int c = 0; c < 64; c++) sm = fmaf(pl[c], fc_w[c * 40 + t], sm);
    lg[t] = sm;
  }
  __syncthreads();
  if (t == 0) {
    float m = -1e30f;
    for (int j = 0; j < 40; j++) m = fmaxf(m, lg[j]);
    float su = 0.f;
    for (int j = 0; j < 40; j++) su += expf(lg[j] - m);
    lse = m + logf(su);
  }
  __syncthreads();
  if (t < 40) out[t] = lg[t] - lse;
}

extern "C" void kernel_launch(void* const* d_in, const int* in_sizes, int n_in,
                              void* d_out, int out_size, void* d_ws, size_t ws_size,
                              hipStream_t stream) {
  const float* x        = (const float*)d_in[0];
  const int*   ei       = (const int*)d_in[1];
  const float* W1       = (const float*)d_in[2];
  const float* att_src1 = (const float*)d_in[3];
  const float* att_dst1 = (const float*)d_in[4];
  const float* b1       = (const float*)d_in[5];
  const float* W2       = (const float*)d_in[6];
  const float* att_src2 = (const float*)d_in[7];
  const float* att_dst2 = (const float*)d_in[8];
  const float* b2       = (const float*)d_in[9];
  const float* fc_w     = (const float*)d_in[10];
  const float* fc_b     = (const float*)d_in[11];
  float* out = (float*)d_out;

  const int N    = in_sizes[0] / 128;  // 50000
  const int E0   = in_sizes[1] / 2;    // 800000
  const int Etot = E0 + N;
  const int NBUCK = (N + 255) >> 8;               // 196
  const int NSC  = (Etot + CHUNK2 - 1) / CHUNK2;  // 416
  const int GBY  = (N + 63) / 64;                 // 782
  const int AGG2_BLOCKS = 2048;

  char* wsb = (char*)d_ws;
  size_t o = 0;
  auto alloc = [&](size_t bytes) { char* p = wsb + o; o += (bytes + 15) & ~(size_t)15; return p; };
  unsigned short* w1t  = (unsigned short*)alloc(256 * 128 * 2);       // transposed [256][128]
  unsigned short* w2t  = (unsigned short*)alloc(64 * 256 * 2);        // transposed [64][256]
  unsigned char*  h1f8 = (unsigned char*)alloc((size_t)N * 256);      // h1 fp8
  unsigned char*  h2   = (unsigned char*)alloc((size_t)N * 64);       // h2 fp8
  unsigned short* out1 = (unsigned short*)alloc((size_t)N * 256 * 2); // bf16
  float* as1  = (float*)alloc((size_t)N * 4 * 4);
  float* ad1  = (float*)alloc((size_t)N * 4 * 4);
  float* as2  = (float*)alloc((size_t)N * 4);
  float* ad2  = (float*)alloc((size_t)N * 4);
  int* rowptr = (int*)alloc((size_t)(N + 1) * 4);
  // zero block: bhist[256] + nhist[N]  (single memset)
  int* bhist  = (int*)alloc((256 + (size_t)N) * 4);
  int* nhist  = bhist + 256;
  int* bucketOff = (int*)alloc(257 * 4);
  int* cursor = (int*)alloc(256 * 4);
  int* pairs  = (int*)alloc((size_t)Etot * 4);
  int* csr_src = (int*)alloc((size_t)Etot * 4);
  float* pooled_grp = (float*)alloc((size_t)PGROUPS * 64 * 4);

  dim3 blk(256);

  // ---- prep: W transpose-cast || bucket+node hist ----
  hipMemsetAsync(bhist, 0, (256 + (size_t)N) * sizeof(int), stream);
  prep_kernel<<<16 + 256, blk, 0, stream>>>(W1, w1t, W2, w2t, ei, bhist, nhist,
                                            E0, Etot, NBUCK, 16, 256);
  bucket_scan_kernel<<<1, blk, 0, stream>>>(bhist, bucketOff, cursor, rowptr + N,
                                            pooled_grp, NBUCK, Etot);
  rowptr_kernel<<<NBUCK, blk, 0, stream>>>(nhist, bucketOff, rowptr, N);

  // ---- gemm1 (64x256 blocks, x read once) || bucket-local pairs scatter ----
  gemm1_scatter_kernel<<<NSC + GBY, blk, 0, stream>>>(
      x, w1t, h1f8, att_src1, att_dst1, as1, ad1, N,
      ei, cursor, pairs, E0, Etot, NBUCK, NSC);
  csr_build_kernel<<<NBUCK, blk, 0, stream>>>(pairs, bucketOff, rowptr, csr_src, N);

  // ---- layer-1 aggregate (quarter-wave, direct idx loads, MLP 8) ----
  aggr1_kernel<<<(N + 15) / 16, blk, 0, stream>>>(rowptr, csr_src, as1, ad1,
                                                  (const uint4*)h1f8, b1, out1, N);

  // ---- layer 2: gemm2 (+alpha2 epilogue), aggregate + grouped pool atomics ----
  gemm2_kernel<<<GBY, blk, 0, stream>>>(out1, w2t, h2, att_src2, att_dst2, as2, ad2, N);
  aggr2_pool_kernel<<<AGG2_BLOCKS, blk, 0, stream>>>(rowptr, csr_src, as2, ad2,
                                                     (const unsigned*)h2, b2, pooled_grp, N);

  // ---- epilogue ----
  pool_head_kernel<<<1, 64, 0, stream>>>(pooled_grp, fc_w, fc_b, out, 1.0f / (float)N);
}

// Round 10
// 216.997 us; speedup vs baseline: 1.1485x; 1.1415x over previous
//
#include <hip/hip_runtime.h>
#include <hip/hip_bf16.h>
#include <math.h>

#define NEG_SLOPE 0.2f
#define CHUNK2 2048
#define PGROUPS 32

typedef __attribute__((ext_vector_type(8))) short bf16x8;
typedef __attribute__((ext_vector_type(4))) float f32x4;
typedef __attribute__((ext_vector_type(2))) float f32x2_t;

__device__ __forceinline__ float lrelu(float a) { return a >= 0.f ? a : NEG_SLOPE * a; }
__device__ __forceinline__ unsigned short f2bu(float v) {
  unsigned u = __float_as_uint(v);
  u += 0x7fffu + ((u >> 16) & 1u);  // RNE
  return (unsigned short)(u >> 16);
}
// fp8 e4m3 (OCP on gfx950) HW conversions
__device__ __forceinline__ unsigned char f2fp8(float v) {
  return (unsigned char)(__builtin_amdgcn_cvt_pk_fp8_f32(v, v, 0, false) & 0xFF);
}

// ==== prep: W1/W2 transposed cast (blocks < wBlocks) | bucket hist ====
__global__ __launch_bounds__(256) void prep_kernel(
    const float* __restrict__ W1, unsigned short* __restrict__ w1t,  // [256][128]
    const float* __restrict__ W2, unsigned short* __restrict__ w2t,  // [64][256]
    const int* __restrict__ ei, int* __restrict__ bhist,
    int E0, int Etot, int NBUCK, int wBlocks, int histBlocks) {
  __shared__ int hsm[256];
  int t = threadIdx.x;
  if (blockIdx.x < (unsigned)wBlocks) {
    const int tot1 = 128 * 256, tot2 = 256 * 64;
    for (int i = blockIdx.x * 256 + t; i < tot1 + tot2; i += wBlocks * 256) {
      if (i < tot1) { int k = i >> 8, n = i & 255; w1t[n * 128 + k] = f2bu(W1[i]); }
      else { int j = i - tot1; int k = j >> 6, n = j & 63; w2t[n * 256 + k] = f2bu(W2[j]); }
    }
  } else {
    int bid = blockIdx.x - wBlocks;
    hsm[t] = 0;
    __syncthreads();
    for (int e = bid * 256 + t; e < Etot; e += histBlocks * 256) {
      int dst = (e < E0) ? ei[E0 + e] : (e - E0);
      atomicAdd(&hsm[dst >> 8], 1);
    }
    __syncthreads();
    if (t < NBUCK && hsm[t]) atomicAdd(&bhist[t], hsm[t]);
  }
}

// ================= bucket scan (also zeroes pooled_grp) =================
__global__ __launch_bounds__(256) void bucket_scan_kernel(const int* __restrict__ bhist,
    int* __restrict__ bucketOff, int* __restrict__ cursor, int* __restrict__ rowptrN,
    float* __restrict__ pooled_grp, int NBUCK, int Etot) {
  __shared__ int s[256];
  int t = threadIdx.x;
  int v = (t < NBUCK) ? bhist[t] : 0;
  s[t] = v;
  __syncthreads();
  for (int off = 1; off < 256; off <<= 1) {
    int u = (t >= off) ? s[t - off] : 0;
    __syncthreads();
    s[t] += u;
    __syncthreads();
  }
  int excl = s[t] - v;
  if (t < NBUCK) { bucketOff[t] = excl; cursor[t] = excl; }
  if (t == 0) { bucketOff[NBUCK] = Etot; *rowptrN = Etot; }
  for (int i = t; i < PGROUPS * 64; i += 256) pooled_grp[i] = 0.f;
}

// ===== gemm1 tile: 64 rows x ALL 256 cols per block (x read ONCE).
__device__ void gemm1_tile(const float* __restrict__ x,
    const unsigned short* __restrict__ BT, unsigned char* __restrict__ C8,
    const float* __restrict__ att_s, const float* __restrict__ att_d,
    float* __restrict__ as_, float* __restrict__ ad_,
    int M, int by, char* smem) {
  unsigned short (*Al)[40] = (unsigned short (*)[40])smem;            // 64*40*2  = 5120 B
  unsigned short (*Bt)[40] = (unsigned short (*)[40])(smem + 5120);   // 256*40*2 = 20480 B
  const int tid = threadIdx.x;
  const int row0 = by * 64;
  const int lane = tid & 63, wave = tid >> 6;
  const int l15 = lane & 15, q = lane >> 4;

  f32x4 acc[4][4] = {};
  const int rr = tid >> 2, rc = (tid & 3) * 8;  // A-stage: row 0..63, k-off {0,8,16,24}

  for (int k0 = 0; k0 < 128; k0 += 32) {
    // stage A from f32 x, cast to bf16 (8 floats/thread)
    float4 v0 = make_float4(0.f, 0.f, 0.f, 0.f), v1 = v0;
    if (row0 + rr < M) {
      const float* ap = x + (size_t)(row0 + rr) * 128 + k0 + rc;
      v0 = *(const float4*)ap;
      v1 = *(const float4*)(ap + 4);
    }
    *(ushort4*)&Al[rr][rc] = make_ushort4(f2bu(v0.x), f2bu(v0.y), f2bu(v0.z), f2bu(v0.w));
    *(ushort4*)&Al[rr][rc + 4] = make_ushort4(f2bu(v1.x), f2bu(v1.y), f2bu(v1.z), f2bu(v1.w));
    // stage B: thread t stages full row t (32 shorts)
    {
      const ushort4* bp = (const ushort4*)(BT + (size_t)tid * 128 + k0);
#pragma unroll
      for (int i = 0; i < 8; i++) *(ushort4*)&Bt[tid][i * 4] = bp[i];
    }
    __syncthreads();
    bf16x8 af[4], bf[4];
#pragma unroll
    for (int mi = 0; mi < 4; mi++)
      af[mi] = *(const bf16x8*)&Al[mi * 16 + l15][q * 8];
#pragma unroll
    for (int ni = 0; ni < 4; ni++)
      bf[ni] = *(const bf16x8*)&Bt[wave * 64 + ni * 16 + l15][q * 8];
#pragma unroll
    for (int mi = 0; mi < 4; mi++)
#pragma unroll
      for (int ni = 0; ni < 4; ni++)
        acc[mi][ni] = __builtin_amdgcn_mfma_f32_16x16x32_bf16(af[mi], bf[ni], acc[mi][ni], 0, 0, 0);
    __syncthreads();
  }
  // epilogue: fp8 store + in-wave alpha (wave == head)
  float atts[4], attd[4];
#pragma unroll
  for (int ni = 0; ni < 4; ni++) {
    atts[ni] = att_s[wave * 64 + ni * 16 + l15];
    attd[ni] = att_d[wave * 64 + ni * 16 + l15];
  }
#pragma unroll
  for (int mi = 0; mi < 4; mi++) {
#pragma unroll
    for (int r = 0; r < 4; r++) {
      int grow = row0 + mi * 16 + q * 4 + r;
      bool ok = grow < M;
      if (ok) {
#pragma unroll
        for (int ni = 0; ni < 4; ni++)
          C8[(size_t)grow * 256 + wave * 64 + ni * 16 + l15] = f2fp8(acc[mi][ni][r]);
      }
      float vs = acc[mi][0][r] * atts[0] + acc[mi][1][r] * atts[1]
               + acc[mi][2][r] * atts[2] + acc[mi][3][r] * atts[3];
      float vd = acc[mi][0][r] * attd[0] + acc[mi][1][r] * attd[1]
               + acc[mi][2][r] * attd[2] + acc[mi][3][r] * attd[3];
#pragma unroll
      for (int off = 1; off < 16; off <<= 1) {
        vs += __shfl_xor(vs, off);
        vd += __shfl_xor(vd, off);
      }
      if (ok && l15 == 0) {
        as_[(size_t)grow * 4 + wave] = vs;
        ad_[(size_t)grow * 4 + wave] = vd;
      }
    }
  }
}

// ================= fused: bucket scatter (blocks < NSC) || gemm1 =================
__global__ __launch_bounds__(256) void gemm1_scatter_kernel(
    const float* __restrict__ x, const unsigned short* __restrict__ BT,
    unsigned char* __restrict__ C8, const float* __restrict__ att_s,
    const float* __restrict__ att_d, float* __restrict__ as_, float* __restrict__ ad_,
    int M, const int* __restrict__ ei, int* __restrict__ cursor, int* __restrict__ pairs,
    int E0, int Etot, int NBUCK, int NSC) {
  __shared__ __align__(16) char smem[25600];
  if (blockIdx.x < (unsigned)NSC) {
    int2* stage = (int2*)smem;            // 16384 B
    int* h = (int*)(smem + 16384);        // 1024 B
    int* base = (int*)(smem + 17408);     // 1024 B
    int t = threadIdx.x;
    int e0 = blockIdx.x * CHUNK2;
    h[t] = 0;
    __syncthreads();
    int cnt = Etot - e0;
    if (cnt > CHUNK2) cnt = CHUNK2;
    for (int i = t; i < cnt; i += 256) {
      int e = e0 + i;
      int s, d;
      if (e < E0) { s = ei[e]; d = ei[E0 + e]; } else { s = d = e - E0; }
      stage[i] = make_int2((s << 8) | (d & 255), d >> 8);
      atomicAdd(&h[d >> 8], 1);
    }
    __syncthreads();
    if (t < NBUCK && h[t]) base[t] = atomicAdd(&cursor[t], h[t]);
    __syncthreads();
    for (int i = t; i < cnt; i += 256) {
      int2 p = stage[i];
      int pos = atomicAdd(&base[p.y], 1);
      pairs[pos] = p.x;
    }
  } else {
    gemm1_tile(x, BT, C8, att_s, att_d, as_, ad_, M, blockIdx.x - NSC, smem);
  }
}

// ================= per-bucket fine CSR (clean, no fences) =================
__global__ __launch_bounds__(256) void csr_build_kernel(const int* __restrict__ pairs,
    const int* __restrict__ bucketOff, int* __restrict__ rowptr, int* __restrict__ csr_src,
    int N) {
  int b = blockIdx.x, t = threadIdx.x;
  int base = bucketOff[b], cnt = bucketOff[b + 1] - base;
  int n0 = b << 8;
  __shared__ int h[256];
  __shared__ int s[256];
  __shared__ int ex[256];
  h[t] = 0;
  __syncthreads();
  for (int i = t; i < cnt; i += 256) atomicAdd(&h[pairs[base + i] & 255], 1);
  __syncthreads();
  int v = h[t];
  s[t] = v;
  __syncthreads();
  for (int off = 1; off < 256; off <<= 1) {
    int u = (t >= off) ? s[t - off] : 0;
    __syncthreads();
    s[t] += u;
    __syncthreads();
  }
  ex[t] = s[t] - v;
  if (n0 + t < N) rowptr[n0 + t] = base + ex[t];
  __syncthreads();
  for (int i = t; i < cnt; i += 256) {
    int p = pairs[base + i];
    int pos = atomicAdd(&ex[p & 255], 1);
    csr_src[base + pos] = ((unsigned)p) >> 8;
  }
}

// accumulate one fp8 16-ch row into 8 float2 accumulators (v_pk_fma_f32 path)
#define ACCV(W, X) do {                                                        \
    f32x2_t w2_; w2_.x = (W); w2_.y = (W);                                     \
    av[0] += w2_ * __builtin_amdgcn_cvt_pk_f32_fp8((X).x, false);              \
    av[1] += w2_ * __builtin_amdgcn_cvt_pk_f32_fp8((X).x, true);               \
    av[2] += w2_ * __builtin_amdgcn_cvt_pk_f32_fp8((X).y, false);              \
    av[3] += w2_ * __builtin_amdgcn_cvt_pk_f32_fp8((X).y, true);               \
    av[4] += w2_ * __builtin_amdgcn_cvt_pk_f32_fp8((X).z, false);              \
    av[5] += w2_ * __builtin_amdgcn_cvt_pk_f32_fp8((X).z, true);               \
    av[6] += w2_ * __builtin_amdgcn_cvt_pk_f32_fp8((X).w, false);              \
    av[7] += w2_ * __builtin_amdgcn_cvt_pk_f32_fp8((X).w, true);               \
  } while (0)

// ====== layer-1 aggregate: quarter-wave per node, 16 ch/lane, direct idx loads, MLP 8 ======
__global__ __launch_bounds__(256) void aggr1_kernel(const int* __restrict__ rowptr,
    const int* __restrict__ csr_src, const float* __restrict__ as_,
    const float* __restrict__ ad_, const uint4* __restrict__ h1f8,  // [N][16] uint4
    const float* __restrict__ b1, unsigned short* __restrict__ out1, int Nn) {
  int lane = threadIdx.x & 63, wv = threadIdx.x >> 6;
  int q = lane >> 4, l15 = lane & 15;
  int n = (blockIdx.x * 4 + wv) * 4 + q;
  if (n >= Nn) return;
  int row = rowptr[n], deg = rowptr[n + 1] - row;
  int hh = l15 >> 2;
  float adv = ad_[n * 4 + hh];
  const uint4* hb = h1f8 + l15;
  f32x2_t av[8] = {};
  float wsum = 0.f;
  for (int s = 0; s < deg; s += 8) {
    int id[8];
    float al[8];
    uint4 xv[8];
#pragma unroll
    for (int u = 0; u < 8; u++) {
      int p = s + u;
      if (p > deg - 1) p = deg - 1;       // clamp: always in-bounds
      id[u] = csr_src[row + p];           // uniform across quarter -> broadcast
    }
#pragma unroll
    for (int u = 0; u < 8; u++) al[u] = as_[id[u] * 4 + hh];
#pragma unroll
    for (int u = 0; u < 8; u++) xv[u] = hb[(size_t)id[u] * 16];
#pragma unroll
    for (int u = 0; u < 8; u++) {
      float w = (s + u < deg) ? __expf(lrelu(al[u] + adv)) : 0.f;
      wsum += w;
      ACCV(w, xv[u]);
    }
  }
  float vinv = 1.f / wsum;
  int c0i = l15 * 16;
  unsigned short ob[16];
#pragma unroll
  for (int k = 0; k < 4; k++) {
    float4 bb = *(const float4*)(b1 + c0i + k * 4);
    float r0 = fmaf(av[k * 2].x, vinv, bb.x);
    float r1 = fmaf(av[k * 2].y, vinv, bb.y);
    float r2 = fmaf(av[k * 2 + 1].x, vinv, bb.z);
    float r3 = fmaf(av[k * 2 + 1].y, vinv, bb.w);
    ob[k * 4 + 0] = f2bu(r0 > 0.f ? r0 : 0.f);
    ob[k * 4 + 1] = f2bu(r1 > 0.f ? r1 : 0.f);
    ob[k * 4 + 2] = f2bu(r2 > 0.f ? r2 : 0.f);
    ob[k * 4 + 3] = f2bu(r3 > 0.f ? r3 : 0.f);
  }
  *(ushort4*)(out1 + (size_t)n * 256 + c0i) = *(ushort4*)&ob[0];
  *(ushort4*)(out1 + (size_t)n * 256 + c0i + 4) = *(ushort4*)&ob[4];
  *(ushort4*)(out1 + (size_t)n * 256 + c0i + 8) = *(ushort4*)&ob[8];
  *(ushort4*)(out1 + (size_t)n * 256 + c0i + 12) = *(ushort4*)&ob[12];
}

// ===== gemm2 (generic small-LDS tile): A bf16 [M][256], BT [64][256] -> h2 fp8 + alpha =====
__global__ __launch_bounds__(256) void gemm2_kernel(const unsigned short* __restrict__ A,
    const unsigned short* __restrict__ BT, unsigned char* __restrict__ C8,
    const float* __restrict__ att_s, const float* __restrict__ att_d,
    float* __restrict__ as_, float* __restrict__ ad_, int M) {
  const int K = 256, Ncol = 64;
  __shared__ __align__(16) char smem[11264];
  unsigned short (*Al)[40] = (unsigned short (*)[40])smem;           // 5120 B
  unsigned short (*Bt)[40] = (unsigned short (*)[40])(smem + 5120);  // 5120 B
  float* sal = (float*)(smem + 10240);  // [2][64]
  float* sad = (float*)(smem + 10752);  // [2][64]
  const int tid = threadIdx.x;
  const int row0 = blockIdx.x * 64;
  const int lane = tid & 63, wave = tid >> 6;
  const int wm = wave >> 1, wn = wave & 1;
  const int l15 = lane & 15, q = lane >> 4;

  f32x4 acc[2][2] = {};
  const int rr = tid >> 2, rc = (tid & 3) * 8;

  for (int k0 = 0; k0 < K; k0 += 32) {
    ushort4 av0 = make_ushort4(0, 0, 0, 0), av1 = av0;
    if (row0 + rr < M) {
      const ushort4* ap = (const ushort4*)(A + (size_t)(row0 + rr) * K + k0 + rc);
      av0 = ap[0]; av1 = ap[1];
    }
    *(ushort4*)&Al[rr][rc] = av0;
    *(ushort4*)&Al[rr][rc + 4] = av1;
    {
      const ushort4* bp = (const ushort4*)(BT + (size_t)rr * K + k0 + rc);
      *(ushort4*)&Bt[rr][rc] = bp[0];
      *(ushort4*)&Bt[rr][rc + 4] = bp[1];
    }
    __syncthreads();
    bf16x8 af[2], bf[2];
#pragma unroll
    for (int mi = 0; mi < 2; mi++)
      af[mi] = *(const bf16x8*)&Al[wm * 32 + mi * 16 + l15][q * 8];
#pragma unroll
    for (int ni = 0; ni < 2; ni++)
      bf[ni] = *(const bf16x8*)&Bt[wn * 32 + ni * 16 + l15][q * 8];
#pragma unroll
    for (int mi = 0; mi < 2; mi++)
#pragma unroll
      for (int ni = 0; ni < 2; ni++)
        acc[mi][ni] = __builtin_amdgcn_mfma_f32_16x16x32_bf16(af[mi], bf[ni], acc[mi][ni], 0, 0, 0);
    __syncthreads();
  }
#pragma unroll
  for (int mi = 0; mi < 2; mi++) {
#pragma unroll
    for (int r = 0; r < 4; r++) {
      int grow = row0 + wm * 32 + mi * 16 + q * 4 + r;
      if (grow < M) {
#pragma unroll
        for (int ni = 0; ni < 2; ni++) {
          int gcol = wn * 32 + ni * 16 + l15;
          C8[(size_t)grow * Ncol + gcol] = f2fp8(acc[mi][ni][r]);
        }
      }
    }
  }
  float atts0 = att_s[wn * 32 + l15], atts1 = att_s[wn * 32 + 16 + l15];
  float attd0 = att_d[wn * 32 + l15], attd1 = att_d[wn * 32 + 16 + l15];
#pragma unroll
  for (int mi = 0; mi < 2; mi++) {
#pragma unroll
    for (int r = 0; r < 4; r++) {
      float vs = acc[mi][0][r] * atts0 + acc[mi][1][r] * atts1;
      float vd = acc[mi][0][r] * attd0 + acc[mi][1][r] * attd1;
#pragma unroll
      for (int off = 1; off < 16; off <<= 1) {
        vs += __shfl_xor(vs, off);
        vd += __shfl_xor(vd, off);
      }
      if (l15 == 0) {
        int rl = wm * 32 + mi * 16 + q * 4 + r;
        sal[wn * 64 + rl] = vs;
        sad[wn * 64 + rl] = vd;
      }
    }
  }
  __syncthreads();
  if (tid < 64) {
    int grow = row0 + tid;
    if (grow < M) {
      as_[grow] = sal[tid] + sal[64 + tid];
      ad_[grow] = sad[tid] + sad[64 + tid];
    }
  }
}

// ====== layer-2 aggregate + relu + pool: direct uniform idx loads, unroll 8, pk-fma ======
__global__ __launch_bounds__(256) void aggr2_pool_kernel(const int* __restrict__ rowptr,
    const int* __restrict__ csr_src, const float* __restrict__ as_,
    const float* __restrict__ ad_, const unsigned* __restrict__ h2f8,
    const float* __restrict__ b2, float* __restrict__ pooled_grp, int Nn) {
  int lane = threadIdx.x & 63, wv = threadIdx.x >> 6;
  int q = lane >> 4, l15 = lane & 15;
  int c0 = l15 * 4;
  const unsigned* hb = h2f8 + l15;
  f32x2_t pv0 = {0.f, 0.f}, pv1 = {0.f, 0.f};
  int stream = (blockIdx.x * 4 + wv) * 4 + q;
  int nstreams = gridDim.x * 16;
  for (int n = stream; n < Nn; n += nstreams) {
    int row = rowptr[n], deg = rowptr[n + 1] - row;
    float adv = ad_[n];
    f32x2_t a01 = {0.f, 0.f}, a23 = {0.f, 0.f};
    float wsum = 0.f;
    for (int s = 0; s < deg; s += 8) {
      int id[8];
      float al[8];
      unsigned xv[8];
#pragma unroll
      for (int u = 0; u < 8; u++) {
        int p = s + u;
        if (p > deg - 1) p = deg - 1;
        id[u] = csr_src[row + p];
      }
#pragma unroll
      for (int u = 0; u < 8; u++) al[u] = as_[id[u]];
#pragma unroll
      for (int u = 0; u < 8; u++) xv[u] = hb[(size_t)id[u] * 16];
#pragma unroll
      for (int u = 0; u < 8; u++) {
        float w = (s + u < deg) ? __expf(lrelu(al[u] + adv)) : 0.f;
        wsum += w;
        f32x2_t w2_; w2_.x = w; w2_.y = w;
        a01 += w2_ * __builtin_amdgcn_cvt_pk_f32_fp8(xv[u], false);
        a23 += w2_ * __builtin_amdgcn_cvt_pk_f32_fp8(xv[u], true);
      }
    }
    float vinv = 1.f / wsum;
    float4 bb = *(const float4*)(b2 + c0);
    float r0 = fmaf(a01.x, vinv, bb.x), r1 = fmaf(a01.y, vinv, bb.y);
    float r2 = fmaf(a23.x, vinv, bb.z), r3 = fmaf(a23.y, vinv, bb.w);
    pv0.x += r0 > 0.f ? r0 : 0.f; pv0.y += r1 > 0.f ? r1 : 0.f;
    pv1.x += r2 > 0.f ? r2 : 0.f; pv1.y += r3 > 0.f ? r3 : 0.f;
  }
  __shared__ float4 sred[4][4][16];
  sred[wv][q][l15] = make_float4(pv0.x, pv0.y, pv1.x, pv1.y);
  __syncthreads();
  if (threadIdx.x < 64) {
    int slot = threadIdx.x >> 2, comp = threadIdx.x & 3;
    float acc = 0.f;
#pragma unroll
    for (int i = 0; i < 4; i++)
#pragma unroll
      for (int j = 0; j < 4; j++) {
        float4 v = sred[i][j][slot];
        acc += comp == 0 ? v.x : (comp == 1 ? v.y : (comp == 2 ? v.z : v.w));
      }
    atomicAdd(&pooled_grp[(blockIdx.x & (PGROUPS - 1)) * 64 + slot * 4 + comp], acc);
  }
}

// ================= pooled_grp[32][64] -> fc + log_softmax (one block) =================
__global__ __launch_bounds__(64) void pool_head_kernel(const float* __restrict__ pooled_grp,
    const float* __restrict__ fc_w, const float* __restrict__ fc_b,
    float* __restrict__ out, float invN) {
  int t = threadIdx.x;
  __shared__ float pl[64];
  __shared__ float lg[40];
  __shared__ float lse;
  float acc = 0.f;
#pragma unroll
  for (int g = 0; g < PGROUPS; g++) acc += pooled_grp[g * 64 + t];
  pl[t] = acc * invN;
  __syncthreads();
  if (t < 40) {
    float sm = fc_b[t];
    for (int c = 0; c < 64; c++) sm = fmaf(pl[c], fc_w[c * 40 + t], sm);
    lg[t] = sm;
  }
  __syncthreads();
  if (t == 0) {
    float m = -1e30f;
    for (int j = 0; j < 40; j++) m = fmaxf(m, lg[j]);
    float su = 0.f;
    for (int j = 0; j < 40; j++) su += expf(lg[j] - m);
    lse = m + logf(su);
  }
  __syncthreads();
  if (t < 40) out[t] = lg[t] - lse;
}

extern "C" void kernel_launch(void* const* d_in, const int* in_sizes, int n_in,
                              void* d_out, int out_size, void* d_ws, size_t ws_size,
                              hipStream_t stream) {
  const float* x        = (const float*)d_in[0];
  const int*   ei       = (const int*)d_in[1];
  const float* W1       = (const float*)d_in[2];
  const float* att_src1 = (const float*)d_in[3];
  const float* att_dst1 = (const float*)d_in[4];
  const float* b1       = (const float*)d_in[5];
  const float* W2       = (const float*)d_in[6];
  const float* att_src2 = (const float*)d_in[7];
  const float* att_dst2 = (const float*)d_in[8];
  const float* b2       = (const float*)d_in[9];
  const float* fc_w     = (const float*)d_in[10];
  const float* fc_b     = (const float*)d_in[11];
  float* out = (float*)d_out;

  const int N    = in_sizes[0] / 128;  // 50000
  const int E0   = in_sizes[1] / 2;    // 800000
  const int Etot = E0 + N;
  const int NBUCK = (N + 255) >> 8;               // 196
  const int NSC  = (Etot + CHUNK2 - 1) / CHUNK2;  // 416
  const int GBY  = (N + 63) / 64;                 // 782
  const int AGG2_BLOCKS = 2048;

  char* wsb = (char*)d_ws;
  size_t o = 0;
  auto alloc = [&](size_t bytes) { char* p = wsb + o; o += (bytes + 15) & ~(size_t)15; return p; };
  unsigned short* w1t  = (unsigned short*)alloc(256 * 128 * 2);       // transposed [256][128]
  unsigned short* w2t  = (unsigned short*)alloc(64 * 256 * 2);        // transposed [64][256]
  unsigned char*  h1f8 = (unsigned char*)alloc((size_t)N * 256);      // h1 fp8
  unsigned char*  h2   = (unsigned char*)alloc((size_t)N * 64);       // h2 fp8
  unsigned short* out1 = (unsigned short*)alloc((size_t)N * 256 * 2); // bf16
  float* as1  = (float*)alloc((size_t)N * 4 * 4);
  float* ad1  = (float*)alloc((size_t)N * 4 * 4);
  float* as2  = (float*)alloc((size_t)N * 4);
  float* ad2  = (float*)alloc((size_t)N * 4);
  int* rowptr = (int*)alloc((size_t)(N + 1) * 4);
  int* bhist  = (int*)alloc(256 * 4);
  int* bucketOff = (int*)alloc(257 * 4);
  int* cursor = (int*)alloc(256 * 4);
  int* pairs  = (int*)alloc((size_t)Etot * 4);
  int* csr_src = (int*)alloc((size_t)Etot * 4);
  float* pooled_grp = (float*)alloc((size_t)PGROUPS * 64 * 4);

  dim3 blk(256);

  // ---- prep: W transpose-cast || bucket hist ----
  hipMemsetAsync(bhist, 0, 256 * sizeof(int), stream);
  prep_kernel<<<16 + 256, blk, 0, stream>>>(W1, w1t, W2, w2t, ei, bhist,
                                            E0, Etot, NBUCK, 16, 256);
  bucket_scan_kernel<<<1, blk, 0, stream>>>(bhist, bucketOff, cursor, rowptr + N,
                                            pooled_grp, NBUCK, Etot);

  // ---- gemm1 (64x256 blocks, x read once, in-wave alpha) || bucket scatter ----
  gemm1_scatter_kernel<<<NSC + GBY, blk, 0, stream>>>(
      x, w1t, h1f8, att_src1, att_dst1, as1, ad1, N,
      ei, cursor, pairs, E0, Etot, NBUCK, NSC);
  csr_build_kernel<<<NBUCK, blk, 0, stream>>>(pairs, bucketOff, rowptr, csr_src, N);

  // ---- layer-1 aggregate (quarter-wave, direct idx loads, MLP 8) ----
  aggr1_kernel<<<(N + 15) / 16, blk, 0, stream>>>(rowptr, csr_src, as1, ad1,
                                                  (const uint4*)h1f8, b1, out1, N);

  // ---- layer 2: gemm2 (+alpha2 epilogue), aggregate + grouped pool atomics ----
  gemm2_kernel<<<GBY, blk, 0, stream>>>(out1, w2t, h2, att_src2, att_dst2, as2, ad2, N);
  aggr2_pool_kernel<<<AGG2_BLOCKS, blk, 0, stream>>>(rowptr, csr_src, as2, ad2,
                                                     (const unsigned*)h2, b2, pooled_grp, N);

  // ---- epilogue ----
  pool_head_kernel<<<1, 64, 0, stream>>>(pooled_grp, fc_w, fc_b, out, 1.0f / (float)N);
}